// Round 11
// baseline (19.221 us; speedup 1.0000x reference)
//
#include <hip/hip_runtime.h>
#include <math.h>

#define BB 512
#define DD 256
#define TMARGIN 0.2f
#define NBLK 256          // trip: 2 anchors per block
#define NTHR 512

typedef _Float16 half_t;

// ---------------- Kernel A: tiled pairwise distances -> fp16 D[512][512] ----------------
// grid (16,16), block 256. 32x32 output tile; panels staged in padded LDS (stride 260 f).
// Block (0,0) additionally: analytic triplet count -> invc, and zeroes out[0].
__global__ void __launch_bounds__(256)
tl_dist(const float* __restrict__ X, const int* __restrict__ labels,
        half_t* __restrict__ D, float* __restrict__ invc, float* __restrict__ out) {
    __shared__ float pi[32][260];      // padded: conflict-free enough (proven R10)
    __shared__ float pj[32][260];
    __shared__ float nish[32], njsh[32];
    __shared__ int   hist[16];
    const int t  = threadIdx.x;
    const int bi = blockIdx.x, bj = blockIdx.y;
    const float4* X4 = (const float4*)X;   // row stride 64 float4

    // stage both panels, fully coalesced (each wave-inst = one 1KB row)
    #pragma unroll
    for (int k = 0; k < 8; ++k) {
        const int idx = t + 256 * k;       // 0..2047
        const int r = idx >> 6, c4 = idx & 63;
        *(float4*)&pi[r][c4 * 4] = X4[(size_t)(bi * 32 + r) * 64 + c4];
        *(float4*)&pj[r][c4 * 4] = X4[(size_t)(bj * 32 + r) * 64 + c4];
    }
    __syncthreads();

    // panel norms: thread (r=t>>3, s=t&7) partial over 8 f4 chunks; 3-step butterfly over s
    {
        const int r = t >> 3, s = t & 7;
        float p1 = 0.f, p2 = 0.f;
        #pragma unroll
        for (int i2 = 0; i2 < 8; ++i2) {
            const int g = s * 8 + i2;
            const float4 a = *(const float4*)&pi[r][g * 4];
            const float4 b = *(const float4*)&pj[r][g * 4];
            p1 += a.x*a.x + a.y*a.y + a.z*a.z + a.w*a.w;
            p2 += b.x*b.x + b.y*b.y + b.z*b.z + b.w*b.w;
        }
        #pragma unroll
        for (int m = 1; m < 8; m <<= 1) {
            p1 += __shfl_xor(p1, m, 64);
            p2 += __shfl_xor(p2, m, 64);
        }
        if (s == 0) { nish[r] = p1; njsh[r] = p2; }
    }
    __syncthreads();

    // 2x2 register tile: rows {ti, ti+16} x cols {tj, tj+16}
    const int ti = t >> 4, tj = t & 15;
    float acc00 = 0.f, acc01 = 0.f, acc10 = 0.f, acc11 = 0.f;
    #pragma unroll 8
    for (int g = 0; g < 64; ++g) {
        const float4 a0 = *(const float4*)&pi[ti     ][g * 4];
        const float4 a1 = *(const float4*)&pi[ti + 16][g * 4];
        const float4 b0 = *(const float4*)&pj[tj     ][g * 4];
        const float4 b1 = *(const float4*)&pj[tj + 16][g * 4];
        acc00 += a0.x*b0.x + a0.y*b0.y + a0.z*b0.z + a0.w*b0.w;
        acc01 += a0.x*b1.x + a0.y*b1.y + a0.z*b1.z + a0.w*b1.w;
        acc10 += a1.x*b0.x + a1.y*b0.y + a1.z*b0.z + a1.w*b0.w;
        acc11 += a1.x*b1.x + a1.y*b1.y + a1.z*b1.z + a1.w*b1.w;
    }

    const float ni0 = nish[ti], ni1 = nish[ti + 16];
    const float nj0 = njsh[tj], nj1 = njsh[tj + 16];
    const int gi0 = bi * 32 + ti, gi1 = gi0 + 16;
    const int gj0 = bj * 32 + tj, gj1 = gj0 + 16;
    const float s00 = ni0 + nj0 - 2.f * acc00;
    const float s01 = ni0 + nj1 - 2.f * acc01;
    const float s10 = ni1 + nj0 - 2.f * acc10;
    const float s11 = ni1 + nj1 - 2.f * acc11;
    D[(size_t)gi0 * BB + gj0] = (half_t)((s00 > 0.f) ? sqrtf(s00) : 0.f);
    D[(size_t)gi0 * BB + gj1] = (half_t)((s01 > 0.f) ? sqrtf(s01) : 0.f);
    D[(size_t)gi1 * BB + gj0] = (half_t)((s10 > 0.f) ? sqrtf(s10) : 0.f);
    D[(size_t)gi1 * BB + gj1] = (half_t)((s11 > 0.f) ? sqrtf(s11) : 0.f);

    // ---- block (0,0): analytic count from labels; zero the output accumulator ----
    if (bi == 0 && bj == 0) {
        if (t < 16) hist[t] = 0;
        __syncthreads();
        atomicAdd(&hist[labels[t] & 15], 1);           // t
        atomicAdd(&hist[labels[t + 256] & 15], 1);     // t+256
        __syncthreads();
        if (t == 0) {
            long long cnt = 0;
            #pragma unroll
            for (int c = 0; c < 16; ++c) {
                const long long n = hist[c];
                cnt += n * (n - 1) * (long long)(BB - n);
            }
            invc[0] = (cnt > 0) ? (1.0f / (float)cnt) : 0.0f;
            out[0]  = 0.0f;                            // re-zeroed every call (replay-safe)
        }
    }
}

// ---------------- Kernel B: per-block triplet partials (2 anchors/block) ----------------
// grid 256 x 512. Reads 2 rows of fp16 D; each block atomicAdds bsum*invc into out.
__global__ void __launch_bounds__(NTHR)
tl_trip(const half_t* __restrict__ D,
        const int* __restrict__ labels,
        const float* __restrict__ invc,
        float* __restrict__ out) {
    __shared__ float drowL[2][520];     // [anchor][col]; slots 512.. = -1e30 sentinel
    __shared__ int   labL[BB];
    __shared__ int   plist[2][520];
    __shared__ int   pcnt[2];
    __shared__ float partf[8];

    const int t   = threadIdx.x;        // 0..511 == column / negative k it owns
    const int ia0 = blockIdx.x * 2;
    const int ia1 = ia0 + 1;

    labL[t] = labels[t];
    if (t < 2) pcnt[t] = 0;
    if (t < 16) drowL[t >> 3][512 + (t & 7)] = -1e30f;   // sentinel pads
    __syncthreads();

    // positive lists (LDS atomics) + distance-row loads overlap
    {
        const int l0 = labL[ia0], l1 = labL[ia1];
        if (labL[t] == l0 && t != ia0) plist[0][atomicAdd(&pcnt[0], 1)] = t;
        if (labL[t] == l1 && t != ia1) plist[1][atomicAdd(&pcnt[1], 1)] = t;
    }
    const float dk0 = (float)D[(size_t)ia0 * BB + t];   // coalesced 2B/lane
    const float dk1 = (float)D[(size_t)ia1 * BB + t];
    drowL[0][t] = dk0;
    drowL[1][t] = dk1;
    __syncthreads();                    // pcnt final, drow visible

    // pad positive lists to multiple of 8 with sentinel index 512
    if (t < 8) {
        int np = pcnt[0], pad = ((np + 7) & ~7) - np;
        if (t < pad) plist[0][np + t] = 512;
    } else if (t < 16) {
        int q = t - 8;
        int np = pcnt[1], pad = ((np + 7) & ~7) - np;
        if (q < pad) plist[1][np + q] = 512;
    }
    __syncthreads();

    // phase 2: thread owns negative k = t for both anchors
    float lsum = 0.0f;
    #pragma unroll
    for (int a = 0; a < 2; ++a) {
        const int li   = labL[ia0 + a];
        const bool neg = (labL[t] != li);
        const float dk = (a == 0) ? dk0 : dk1;
        const int npp  = (pcnt[a] + 7) & ~7;
        float s = 0.0f;
        for (int p = 0; p < npp; p += 8) {
            float dj0 = drowL[a][plist[a][p + 0]];   // uniform -> LDS broadcast
            float dj1 = drowL[a][plist[a][p + 1]];
            float dj2 = drowL[a][plist[a][p + 2]];
            float dj3 = drowL[a][plist[a][p + 3]];
            float dj4 = drowL[a][plist[a][p + 4]];
            float dj5 = drowL[a][plist[a][p + 5]];
            float dj6 = drowL[a][plist[a][p + 6]];
            float dj7 = drowL[a][plist[a][p + 7]];
            s += fmaxf(dj0 - dk + TMARGIN, 0.0f);
            s += fmaxf(dj1 - dk + TMARGIN, 0.0f);
            s += fmaxf(dj2 - dk + TMARGIN, 0.0f);
            s += fmaxf(dj3 - dk + TMARGIN, 0.0f);
            s += fmaxf(dj4 - dk + TMARGIN, 0.0f);
            s += fmaxf(dj5 - dk + TMARGIN, 0.0f);
            s += fmaxf(dj6 - dk + TMARGIN, 0.0f);
            s += fmaxf(dj7 - dk + TMARGIN, 0.0f);
        }
        if (neg) lsum += s;
    }

    // block reduction; single atomicAdd of pre-scaled partial into out
    #pragma unroll
    for (int o = 32; o > 0; o >>= 1) lsum += __shfl_xor(lsum, o, 64);
    if ((t & 63) == 0) partf[t >> 6] = lsum;
    __syncthreads();
    if (t == 0) {
        float bsum = 0.0f;
        #pragma unroll
        for (int w2 = 0; w2 < 8; ++w2) bsum += partf[w2];
        atomicAdd(out, bsum * invc[0]);   // invc from node 1 (kernel-boundary coherent)
    }
}

extern "C" void kernel_launch(void* const* d_in, const int* in_sizes, int n_in,
                              void* d_out, int out_size, void* d_ws, size_t ws_size,
                              hipStream_t stream) {
    const float* X      = (const float*)d_in[0];   // [512,256] f32
    const int*   labels = (const int*)d_in[1];     // [512] int

    float*  invc = (float*)d_ws;                          // 1 f32, rewritten each call
    half_t* D    = (half_t*)((char*)d_ws + 4096);         // 512 KB fp16 distance matrix

    // NOTE: no hipMemsetAsync (fill node ~13 us, R4->R5), no 3rd kernel node (~2 us, R10),
    // no in-kernel device-scope fences (~5 us, R9). Node1 re-zeroes out[0] every call.
    tl_dist<<<dim3(16, 16), 256, 0, stream>>>(X, labels, D, invc, (float*)d_out);
    tl_trip<<<NBLK, NTHR, 0, stream>>>(D, labels, invc, (float*)d_out);
}

// Round 13
// 15.804 us; speedup vs baseline: 1.2163x; 1.2163x over previous
//
#include <hip/hip_runtime.h>
#include <math.h>

#define BB 512
#define DD 256
#define TMARGIN 0.2f
#define NBLK 256          // 2 anchors per block
#define NTHR 512          // thread t owns column/negative j = t
#define PSTR 9            // padded LDS stride for partials (gcd(9,32)=1 -> conflict-free reads)

// ---------------- Kernel 1: per-block triplet partials (2 anchors/block) ----------------
// grid 256 x 512. Phase 1: 8-lane-cooperative coalesced row reads; partials transposed
// through padded LDS (no cross-lane shuffles, no divergent gather).  [R8-proven: 15.9 us]
__global__ void __launch_bounds__(NTHR, 2)
tl_part(const float* __restrict__ X,
        const int* __restrict__ labels,
        float* __restrict__ psum,
        unsigned int* __restrict__ pcount) {
    __shared__ float pA[BB * PSTR];     // 18 KB: dot(x_a0, x_row) partials, [row][chunk-class]
    __shared__ float pBt[BB * PSTR];    // 18 KB: dot(x_a1, x_row) partials
    __shared__ float pN[BB * PSTR];     // 18 KB: ||x_row||^2 partials
    __shared__ float drowL[2][520];     // [anchor][col]; slots 512.. = -1e30 sentinel
    __shared__ int   labL[BB];
    __shared__ int   plist[2][520];
    __shared__ int   pcnt[2];
    __shared__ float nsh[2];            // anchor squared norms
    __shared__ float partf[8];

    const int t   = threadIdx.x;        // 0..511 == row/column j it owns
    const int ia0 = blockIdx.x * 2;
    const int ia1 = ia0 + 1;

    labL[t] = labels[t];
    if (t < 2) pcnt[t] = 0;
    if (t < 16) drowL[t >> 3][512 + (t & 7)] = -1e30f;   // sentinel pads
    __syncthreads();

    // ---- build positive lists (LDS atomics; complete by the barrier after phase 1) ----
    {
        const int l0 = labL[ia0], l1 = labL[ia1];
        if (labL[t] == l0 && t != ia0) plist[0][atomicAdd(&pcnt[0], 1)] = t;
        if (labL[t] == l1 && t != ia1) plist[1][atomicAdd(&pcnt[1], 1)] = t;
    }

    // ---- phase 1: coalesced cooperative dots, partials via padded-LDS transpose ----
    // Pass p: 8-lane group g computes row wbase+8p+g; lane class c reads f4 chunks c+8i
    // (group reads 128 B contiguous). Partial sums land in LDS[row][c], stride 9.
    const int l     = t & 63;
    const int wbase = t & ~63;          // wave's 64-row base
    const int g     = l >> 3;           // row-subgroup within a pass
    const int c     = l & 7;            // f4-chunk class
    const float4* X4 = (const float4*)X;   // row stride = 64 float4

    float4 u[8], w[8];                  // anchor fragments for chunk classes c+8i
    #pragma unroll
    for (int i = 0; i < 8; ++i) {
        u[i] = X4[ia0 * 64 + c + 8 * i];
        w[i] = X4[ia1 * 64 + c + 8 * i];
    }

    #pragma unroll
    for (int p = 0; p < 8; ++p) {
        const int row = wbase + p * 8 + g;
        const float4* xr = X4 + (size_t)row * 64;
        float pa0 = 0.f, pa1 = 0.f, pnn = 0.f;
        #pragma unroll
        for (int i = 0; i < 8; ++i) {
            const float4 v = xr[c + 8 * i];
            pa0 += u[i].x * v.x + u[i].y * v.y + u[i].z * v.z + u[i].w * v.w;
            pa1 += w[i].x * v.x + w[i].y * v.y + w[i].z * v.z + w[i].w * v.w;
            pnn += v.x * v.x + v.y * v.y + v.z * v.z + v.w * v.w;
        }
        pA [row * PSTR + c] = pa0;      // wave-internal: written & read by this wave only
        pBt[row * PSTR + c] = pa1;
        pN [row * PSTR + c] = pnn;
    }

    // gather: thread t sums its row's 8 partials per quantity (conflict-free reads)
    float a0 = 0.f, a1 = 0.f, nn = 0.f;
    #pragma unroll
    for (int k = 0; k < 8; ++k) {
        a0 += pA [t * PSTR + k];
        a1 += pBt[t * PSTR + k];
        nn += pN [t * PSTR + k];
    }

    if (t == ia0) nsh[0] = nn;          // anchor norms from diagonal threads
    if (t == ia1) nsh[1] = nn;
    __syncthreads();

    // ---- distances for column t vs both anchors ----
    float dk0, dk1;
    {
        const float s0 = nsh[0] + nn - 2.0f * a0;
        const float s1 = nsh[1] + nn - 2.0f * a1;
        dk0 = (s0 > 0.0f) ? sqrtf(s0) : 0.0f;
        dk1 = (s1 > 0.0f) ? sqrtf(s1) : 0.0f;
        drowL[0][t] = dk0;
        drowL[1][t] = dk1;
    }
    // pad positive lists to multiple of 8 with sentinel index 512
    if (t < 8) {
        int np = pcnt[0], pad = ((np + 7) & ~7) - np;
        if (t < pad) plist[0][np + t] = 512;
    } else if (t < 16) {
        int q = t - 8;
        int np = pcnt[1], pad = ((np + 7) & ~7) - np;
        if (q < pad) plist[1][np + q] = 512;
    }
    __syncthreads();

    // ---- phase 2: thread owns negative k = t for both anchors ----
    float lsum = 0.0f;
    #pragma unroll
    for (int a = 0; a < 2; ++a) {
        const int li   = labL[ia0 + a];
        const bool neg = (labL[t] != li);
        const float dk = (a == 0) ? dk0 : dk1;
        const int npp  = (pcnt[a] + 7) & ~7;
        float s = 0.0f;
        for (int p = 0; p < npp; p += 8) {
            float dj0 = drowL[a][plist[a][p + 0]];   // uniform -> LDS broadcast
            float dj1 = drowL[a][plist[a][p + 1]];
            float dj2 = drowL[a][plist[a][p + 2]];
            float dj3 = drowL[a][plist[a][p + 3]];
            float dj4 = drowL[a][plist[a][p + 4]];
            float dj5 = drowL[a][plist[a][p + 5]];
            float dj6 = drowL[a][plist[a][p + 6]];
            float dj7 = drowL[a][plist[a][p + 7]];
            s += fmaxf(dj0 - dk + TMARGIN, 0.0f);
            s += fmaxf(dj1 - dk + TMARGIN, 0.0f);
            s += fmaxf(dj2 - dk + TMARGIN, 0.0f);
            s += fmaxf(dj3 - dk + TMARGIN, 0.0f);
            s += fmaxf(dj4 - dk + TMARGIN, 0.0f);
            s += fmaxf(dj5 - dk + TMARGIN, 0.0f);
            s += fmaxf(dj6 - dk + TMARGIN, 0.0f);
            s += fmaxf(dj7 - dk + TMARGIN, 0.0f);
        }
        if (neg) lsum += s;
    }

    // ---- block reduction, write this block's partial to its own slot ----
    #pragma unroll
    for (int o = 32; o > 0; o >>= 1) lsum += __shfl_xor(lsum, o, 64);
    if ((t & 63) == 0) partf[t >> 6] = lsum;
    __syncthreads();
    if (t == 0) {
        float bsum = 0.0f;
        #pragma unroll
        for (int w2 = 0; w2 < 8; ++w2) bsum += partf[w2];
        unsigned int bcnt = 0;
        #pragma unroll
        for (int a = 0; a < 2; ++a) {
            unsigned int np = (unsigned int)pcnt[a];
            bcnt += np * (unsigned int)(BB - 1 - np);
        }
        psum[blockIdx.x]   = bsum;     // plain stores; kernel-boundary coherence
        pcount[blockIdx.x] = bcnt;
    }
}

// ---------------- Kernel 2: reduce 256 partials, finalize ----------------
// 1 block x 256 threads
__global__ void tl_reduce(const float* __restrict__ psum,
                          const unsigned int* __restrict__ pcount,
                          float* __restrict__ out) {
    __shared__ float        sf[4];
    __shared__ unsigned int sc[4];
    const int t = threadIdx.x;
    float        s = psum[t];
    unsigned int c = pcount[t];
    #pragma unroll
    for (int o = 32; o > 0; o >>= 1) {
        s += __shfl_xor(s, o, 64);
        c += __shfl_xor(c, o, 64);
    }
    if ((t & 63) == 0) { sf[t >> 6] = s; sc[t >> 6] = c; }
    __syncthreads();
    if (t == 0) {
        float        tt = sf[0] + sf[1] + sf[2] + sf[3];
        unsigned int cc = sc[0] + sc[1] + sc[2] + sc[3];
        out[0] = (cc > 0u) ? (tt / (float)cc) : 0.0f;
    }
}

extern "C" void kernel_launch(void* const* d_in, const int* in_sizes, int n_in,
                              void* d_out, int out_size, void* d_ws, size_t ws_size,
                              hipStream_t stream) {
    const float* X      = (const float*)d_in[0];   // [512,256] f32
    const int*   labels = (const int*)d_in[1];     // [512] int

    float*        psum   = (float*)d_ws;                          // 256 f32, all rewritten each call
    unsigned int* pcount = (unsigned int*)((char*)d_ws + 1024);   // 256 u32, all rewritten each call

    // NOTE (session ledger): no hipMemsetAsync fill node (~13 us in replay, R4->R5);
    // no in-kernel threadfence finalize (~5 us, R9); no fence-free ticket finalize
    // (RACES on multi-XCD — absmax 4.9e-3, R12). Two nodes, kernel-boundary coherence.
    tl_part<<<NBLK, NTHR, 0, stream>>>(X, labels, psum, pcount);
    tl_reduce<<<1, 256, 0, stream>>>(psum, pcount, (float*)d_out);
}